// Round 1
// baseline (927.511 us; speedup 1.0000x reference)
//
#include <hip/hip_runtime.h>
#include <cstdint>
#include <cstddef>

typedef unsigned int u32;
typedef unsigned short u16;
typedef __attribute__((ext_vector_type(8))) short short8;   // 8 bf16 = 4 VGPRs (MFMA A/B frag)
typedef __attribute__((ext_vector_type(4))) float f32x4;    // MFMA C/D frag

#define S_LEN 1024
#define BATCH 16
#define NHEAD 8
#define DMODEL 512
#define KHD 64

__device__ __forceinline__ u16 f2bf(float f) {
    u32 u = __float_as_uint(f);
    return (u16)((u + 0x7fffu + ((u >> 16) & 1u)) >> 16);   // RTNE
}

// ---------------------------------------------------------------------------
// Projection + per-head L2 norm.
// proj[b,h,s,k] = sum_d x[s,b,d] * W[h*64+k][d]; normalize over k (64);
// store bf16 as [B][H][S][64].
// Block: 256 thr, tile = 32 rows (s) x 512 cols (h*64+k), K-loop over D=512.
// Thread tile: 4 rows x 16 cols (cols cg*16..+15 lie inside head cg>>2).
// ---------------------------------------------------------------------------
__global__ __launch_bounds__(256) void proj_norm_kernel(
    const float* __restrict__ xq, const float* __restrict__ xk, const float* __restrict__ xv,
    const float* __restrict__ WQ, const float* __restrict__ WK, const float* __restrict__ WV,
    u16* __restrict__ oq, u16* __restrict__ ok, u16* __restrict__ ov)
{
    __shared__ __align__(16) float Alds[32][17];     // +1 pad
    __shared__ __align__(16) float Wlds[16][516];    // [kk][col], +4 pad
    const int t = blockIdx.z;
    const float* __restrict__ x  = (t == 0) ? xq : (t == 1) ? xk : xv;
    const float* __restrict__ W  = (t == 0) ? WQ : (t == 1) ? WK : WV;
    u16* __restrict__ outp       = (t == 0) ? oq : (t == 1) ? ok : ov;

    const int tid = threadIdx.x;
    const int b   = blockIdx.y;
    const int s0  = blockIdx.x * 32;
    const int cg  = tid & 31;      // col group: cols cg*16..+15
    const int rg  = tid >> 5;      // row group: rows rg*4..+3

    float acc[4][16];
#pragma unroll
    for (int i = 0; i < 4; i++)
#pragma unroll
        for (int j = 0; j < 16; j++) acc[i][j] = 0.0f;

    for (int kt = 0; kt < DMODEL; kt += 16) {
        // stage A tile: 32 rows x 16 d  (1 float2 per thread)
        {
            const int row = tid >> 3;
            const int dp  = (tid & 7) * 2;
            const float2 av = *(const float2*)(x + ((size_t)(s0 + row) * BATCH + b) * DMODEL + kt + dp);
            Alds[row][dp]     = av.x;
            Alds[row][dp + 1] = av.y;
        }
        // stage W tile transposed: Wlds[kk][hk] = W[hk][kt+kk]  (8 float4/thread)
#pragma unroll
        for (int ii = 0; ii < 8; ii++) {
            const int fi  = tid + ii * 256;        // 0..2047
            const int hk  = fi >> 2;               // 0..511
            const int qd  = (fi & 3) * 4;          // 0,4,8,12
            const float4 w4 = *(const float4*)(W + (size_t)hk * DMODEL + kt + qd);
            Wlds[qd + 0][hk] = w4.x;
            Wlds[qd + 1][hk] = w4.y;
            Wlds[qd + 2][hk] = w4.z;
            Wlds[qd + 3][hk] = w4.w;
        }
        __syncthreads();
#pragma unroll
        for (int kk = 0; kk < 16; kk++) {
            float av[4];
#pragma unroll
            for (int i = 0; i < 4; i++) av[i] = Alds[rg * 4 + i][kk];
            float wv[16];
            const float4* wr = (const float4*)&Wlds[kk][cg * 16];
#pragma unroll
            for (int j = 0; j < 4; j++) {
                const float4 t4 = wr[j];
                wv[j * 4 + 0] = t4.x; wv[j * 4 + 1] = t4.y;
                wv[j * 4 + 2] = t4.z; wv[j * 4 + 3] = t4.w;
            }
#pragma unroll
            for (int i = 0; i < 4; i++)
#pragma unroll
                for (int j = 0; j < 16; j++)
                    acc[i][j] = fmaf(av[i], wv[j], acc[i][j]);
        }
        __syncthreads();
    }

    // L2 norm per (row, head): this thread's 16 cols + 3 neighbor lanes = 64 cols of head
    const int h  = cg >> 2;
    const int k0 = (cg & 3) * 16;
#pragma unroll
    for (int i = 0; i < 4; i++) {
        float ss = 0.0f;
#pragma unroll
        for (int j = 0; j < 16; j++) ss += acc[i][j] * acc[i][j];
        ss += __shfl_xor(ss, 1);
        ss += __shfl_xor(ss, 2);
        const float sc = 1.0f / fmaxf(sqrtf(ss), 1e-12f);
        u16* op = outp + (((size_t)b * NHEAD + h) * S_LEN + (s0 + rg * 4 + i)) * KHD + k0;
        short8 st0, st1;
#pragma unroll
        for (int j = 0; j < 8; j++) st0[j] = (short)f2bf(acc[i][j] * sc);
#pragma unroll
        for (int j = 0; j < 8; j++) st1[j] = (short)f2bf(acc[i][j + 8] * sc);
        *(short8*)(op)     = st0;
        *(short8*)(op + 8) = st1;
    }
}

// ---------------------------------------------------------------------------
// Flash attention: per (b,h), 64 q-rows per block (16 per wave), 32-key tiles.
// wq/wk/wv are bf16 [B][H][S][64]. Output concat fp32 [S][B][512] (= d_out).
// MFMA 16x16x32_bf16, layouts (m89/m120-verified):
//   A: m=lane&15, k=quad*8+j ; B: n=lane&15, k=quad*8+j ; D: col=lane&15, row=quad*4+reg
// ---------------------------------------------------------------------------
__global__ __launch_bounds__(256) void attn_kernel(
    const u16* __restrict__ wq, const u16* __restrict__ wk, const u16* __restrict__ wv,
    float* __restrict__ concat)
{
    __shared__ __align__(16) u16 Klds[32 * 72];       // [key][kdim], stride 72
    __shared__ __align__(16) u16 VTlds[64 * 40];      // [vcol][key], stride 40
    __shared__ __align__(16) u16 Plds[4][16 * 40];    // per-wave [qrow][key], stride 40

    const int tid  = threadIdx.x;
    const int wave = tid >> 6;
    const int lane = tid & 63;
    const int m16  = lane & 15;
    const int quad = lane >> 4;
    const int qt   = blockIdx.x;        // 0..15  (64 q rows each)
    const int bh   = blockIdx.y;        // 0..127 = b*8+h

    const u16* Qb = wq + (size_t)bh * S_LEN * KHD;
    const u16* Kb = wk + (size_t)bh * S_LEN * KHD;
    const u16* Vb = wv + (size_t)bh * S_LEN * KHD;

    // persistent Q A-frags for this wave's 16 rows
    const int qrow = qt * 64 + wave * 16 + m16;
    const short8 aq0 = *(const short8*)(Qb + (size_t)qrow * KHD + quad * 8);
    const short8 aq1 = *(const short8*)(Qb + (size_t)qrow * KHD + 32 + quad * 8);

    f32x4 o[4] = {};                           // O accumulator, rows quad*4+r, cols nt2*16+m16
    float mold[4] = {-1e30f, -1e30f, -1e30f, -1e30f};
    float lsum[4] = {0.0f, 0.0f, 0.0f, 0.0f};
    const float iscale = 0.125f;               // 1/sqrt(64)
    const float LOG2E  = 1.4426950408889634f;

    for (int it = 0; it < S_LEN / 32; it++) {
        const int kt0 = it * 32;
        __syncthreads();   // previous-iteration LDS reads done before overwrite
        // stage K (row-major) and V (transposed) for 32 keys; 1 short8 each per thread
        {
            const int row = tid >> 3;          // 0..31 key
            const int c8  = (tid & 7) * 8;     // 0..56 dim
            const short8 kv = *(const short8*)(Kb + (size_t)(kt0 + row) * KHD + c8);
            *(short8*)&Klds[row * 72 + c8] = kv;
            const short8 vv = *(const short8*)(Vb + (size_t)(kt0 + row) * KHD + c8);
#pragma unroll
            for (int u = 0; u < 8; u++) VTlds[(c8 + u) * 40 + row] = (u16)vv[u];
        }
        __syncthreads();

        // scores: two 16x16 tiles (nt = key sub-tile)
        f32x4 sc[2];
#pragma unroll
        for (int nt = 0; nt < 2; nt++) {
            const short8 b0 = *(const short8*)&Klds[(nt * 16 + m16) * 72 + quad * 8];
            const short8 b1 = *(const short8*)&Klds[(nt * 16 + m16) * 72 + 32 + quad * 8];
            f32x4 c = {};
            c = __builtin_amdgcn_mfma_f32_16x16x32_bf16(aq0, b0, c, 0, 0, 0);
            c = __builtin_amdgcn_mfma_f32_16x16x32_bf16(aq1, b1, c, 0, 0, 0);
            sc[nt] = c;
        }

        // online softmax per q-row (rows quad*4+r live in this lane's regs)
        float alpha[4];
#pragma unroll
        for (int r = 0; r < 4; r++) {
            const float s0v = sc[0][r] * iscale;
            const float s1v = sc[1][r] * iscale;
            float mxr = fmaxf(s0v, s1v);
            mxr = fmaxf(mxr, __shfl_xor(mxr, 1));
            mxr = fmaxf(mxr, __shfl_xor(mxr, 2));
            mxr = fmaxf(mxr, __shfl_xor(mxr, 4));
            mxr = fmaxf(mxr, __shfl_xor(mxr, 8));
            const float mnew = fmaxf(mold[r], mxr);
            alpha[r] = exp2f((mold[r] - mnew) * LOG2E);
            const float p0 = exp2f((s0v - mnew) * LOG2E);
            const float p1 = exp2f((s1v - mnew) * LOG2E);
            float rs = p0 + p1;
            rs += __shfl_xor(rs, 1);
            rs += __shfl_xor(rs, 2);
            rs += __shfl_xor(rs, 4);
            rs += __shfl_xor(rs, 8);
            lsum[r] = lsum[r] * alpha[r] + rs;
            mold[r] = mnew;
            // P (C-layout) -> LDS (A-layout round-trip), wave-private region
            Plds[wave][(quad * 4 + r) * 40 + m16]      = f2bf(p0);
            Plds[wave][(quad * 4 + r) * 40 + 16 + m16] = f2bf(p1);
        }
        __syncthreads();   // order P write -> P read (waves uniform, cheap)

        // PV: P(16x32) @ V(32x64), one MFMA per 16-col slab
        const short8 pa = *(const short8*)&Plds[wave][m16 * 40 + quad * 8];
#pragma unroll
        for (int nt2 = 0; nt2 < 4; nt2++) {
            const short8 vb = *(const short8*)&VTlds[(nt2 * 16 + m16) * 40 + quad * 8];
#pragma unroll
            for (int r = 0; r < 4; r++) o[nt2][r] *= alpha[r];
            o[nt2] = __builtin_amdgcn_mfma_f32_16x16x32_bf16(pa, vb, o[nt2], 0, 0, 0);
        }
    }

    // epilogue: divide by l, write concat[s][b][h*64+col] (fp32, = d_out)
    const int b = bh >> 3, h = bh & 7;
#pragma unroll
    for (int r = 0; r < 4; r++) {
        const float inv = 1.0f / lsum[r];
        const int row = qt * 64 + wave * 16 + quad * 4 + r;
        float* cp = concat + ((size_t)row * BATCH + b) * (NHEAD * KHD) + h * KHD;
#pragma unroll
        for (int nt2 = 0; nt2 < 4; nt2++)
            cp[nt2 * 16 + m16] = o[nt2][r] * inv;
    }
}

// ---------------------------------------------------------------------------
// Output projection, in-place on d_out:
// out[i][d] = sum_j concat[i][j] * Wout[d][j], i = s*16+b (16384 rows).
// Each block reads ONLY the 32 rows it writes -> in-place safe.
// ---------------------------------------------------------------------------
__global__ __launch_bounds__(256) void out_proj_kernel(
    float* __restrict__ io, const float* __restrict__ Wout)
{
    __shared__ __align__(16) float Alds[32][17];
    __shared__ __align__(16) float Wlds[16][516];   // [kk][d] = Wout[d][kt+kk]
    const int tid = threadIdx.x;
    const int r0  = blockIdx.x * 32;
    const int cg  = tid & 31;
    const int rg  = tid >> 5;

    float acc[4][16];
#pragma unroll
    for (int i = 0; i < 4; i++)
#pragma unroll
        for (int j = 0; j < 16; j++) acc[i][j] = 0.0f;

    for (int kt = 0; kt < DMODEL; kt += 16) {
        {
            const int row = tid >> 3;
            const int dp  = (tid & 7) * 2;
            const float2 av = *(const float2*)(io + (size_t)(r0 + row) * DMODEL + kt + dp);
            Alds[row][dp]     = av.x;
            Alds[row][dp + 1] = av.y;
        }
#pragma unroll
        for (int ii = 0; ii < 8; ii++) {
            const int fi = tid + ii * 256;
            const int d  = fi >> 2;
            const int qd = (fi & 3) * 4;
            const float4 w4 = *(const float4*)(Wout + (size_t)d * DMODEL + kt + qd);
            Wlds[qd + 0][d] = w4.x;
            Wlds[qd + 1][d] = w4.y;
            Wlds[qd + 2][d] = w4.z;
            Wlds[qd + 3][d] = w4.w;
        }
        __syncthreads();
#pragma unroll
        for (int kk = 0; kk < 16; kk++) {
            float av[4];
#pragma unroll
            for (int i = 0; i < 4; i++) av[i] = Alds[rg * 4 + i][kk];
            float wv[16];
            const float4* wr = (const float4*)&Wlds[kk][cg * 16];
#pragma unroll
            for (int j = 0; j < 4; j++) {
                const float4 t4 = wr[j];
                wv[j * 4 + 0] = t4.x; wv[j * 4 + 1] = t4.y;
                wv[j * 4 + 2] = t4.z; wv[j * 4 + 3] = t4.w;
            }
#pragma unroll
            for (int i = 0; i < 4; i++)
#pragma unroll
                for (int j = 0; j < 16; j++)
                    acc[i][j] = fmaf(av[i], wv[j], acc[i][j]);
        }
        __syncthreads();
    }
#pragma unroll
    for (int i = 0; i < 4; i++) {
        float* op = io + (size_t)(r0 + rg * 4 + i) * DMODEL + cg * 16;
#pragma unroll
        for (int j = 0; j < 4; j++) {
            float4 v4;
            v4.x = acc[i][j * 4 + 0]; v4.y = acc[i][j * 4 + 1];
            v4.z = acc[i][j * 4 + 2]; v4.w = acc[i][j * 4 + 3];
            *(float4*)(op + j * 4) = v4;
        }
    }
}

extern "C" void kernel_launch(void* const* d_in, const int* in_sizes, int n_in,
                              void* d_out, int out_size, void* d_ws, size_t ws_size,
                              hipStream_t stream) {
    const float* q    = (const float*)d_in[0];
    const float* k    = (const float*)d_in[1];
    const float* v    = (const float*)d_in[2];
    const float* WQ   = (const float*)d_in[3];
    const float* WK   = (const float*)d_in[4];
    const float* WV   = (const float*)d_in[5];
    const float* Wout = (const float*)d_in[6];
    float* out = (float*)d_out;

    // ws: bf16 wq/wk/wv, each B*H*S*64 = 8.39M elements (16.8 MB) -> 50.3 MB total
    const size_t per = (size_t)BATCH * NHEAD * S_LEN * KHD;
    u16* wqs = (u16*)d_ws;
    u16* wks = wqs + per;
    u16* wvs = wks + per;

    dim3 gp(S_LEN / 32, BATCH, 3);
    proj_norm_kernel<<<gp, 256, 0, stream>>>(q, k, v, WQ, WK, WV, wqs, wks, wvs);

    dim3 ga(S_LEN / 64, BATCH * NHEAD);
    attn_kernel<<<ga, 256, 0, stream>>>(wqs, wks, wvs, out);   // concat -> d_out

    out_proj_kernel<<<(S_LEN * BATCH) / 32, 256, 0, stream>>>(out, Wout);
}

// Round 2
// 430.559 us; speedup vs baseline: 2.1542x; 2.1542x over previous
//
#include <hip/hip_runtime.h>
#include <cstdint>
#include <cstddef>

typedef unsigned int u32;
typedef unsigned short u16;
typedef __attribute__((ext_vector_type(8))) short short8;   // 8 bf16 = 4 VGPRs (MFMA A/B frag)
typedef __attribute__((ext_vector_type(4))) float f32x4;    // MFMA C/D frag

#define S_LEN 1024
#define BATCH 16
#define NHEAD 8
#define DMODEL 512
#define KHD 64
#define NROW (S_LEN * BATCH)          // 16384 GEMM rows

__device__ __forceinline__ u16 f2bf(float f) {
    u32 u = __float_as_uint(f);
    return (u16)((u + 0x7fffu + ((u >> 16) & 1u)) >> 16);   // RTNE
}

__device__ __forceinline__ void gl_lds16(const void* g, void* l) {
    __builtin_amdgcn_global_load_lds(
        (const __attribute__((address_space(1))) void*)(uintptr_t)g,
        (__attribute__((address_space(3))) void*)(uintptr_t)l, 16, 0, 0);
}

// ---------------------------------------------------------------------------
// Convert the 4 weight matrices (512x512 fp32) to bf16, packed [4][512*512].
// ---------------------------------------------------------------------------
__global__ __launch_bounds__(256) void wcvt_kernel(
    const float* __restrict__ WQ, const float* __restrict__ WK,
    const float* __restrict__ WV, const float* __restrict__ Wo,
    u16* __restrict__ dst)
{
    const int m = blockIdx.y;
    const float* __restrict__ src = (m == 0) ? WQ : (m == 1) ? WK : (m == 2) ? WV : Wo;
    const int idx = (blockIdx.x * 256 + threadIdx.x) * 4;
    const float4 v = *(const float4*)(src + idx);
    u16 r[4];
    r[0] = f2bf(v.x); r[1] = f2bf(v.y); r[2] = f2bf(v.z); r[3] = f2bf(v.w);
    *(uint2*)(dst + (size_t)m * DMODEL * DMODEL + idx) = *(uint2*)r;
}

// ---------------------------------------------------------------------------
// bf16-MFMA GEMM, 128x128 tile, BK=64, out[i][n] = sum_d A[i][d] * B[n][d].
// A: fp32 row-major [16384][512], converted to bf16 in-kernel (ds_write path,
//    padded LDS stride 72 -> conflict-free).
// B: bf16 row-major [512][512] via global_load_lds width=16 with XOR chunk
//    swizzle folded into the per-lane GLOBAL address (LDS side stays
//    lane-contiguous as required) -> conflict-free b128 frag reads.
// NORM=1: per-head L2-norm epilogue, bf16 out [B][H][S][64], z picks q/k/v.
// NORM=0: plain fp32 epilogue to outP (in-place safe: block reads only the
//         128 rows it writes).
// ---------------------------------------------------------------------------
template<int NORM>
__global__ __launch_bounds__(256) void gemm_kernel(
    const float* __restrict__ A0, const float* __restrict__ A1, const float* __restrict__ A2,
    const u16* __restrict__ Wb,     // base of bf16 weights; + z*512*512
    u16* __restrict__ outN,         // NORM: base of [3][B][H][S][64]
    float* __restrict__ outP)       // !NORM: [16384][512]
{
    __shared__ __align__(16) u16 Alds[128 * 72];
    __shared__ __align__(16) u16 Blds[128 * 64];

    const int tid  = threadIdx.x;
    const int wave = tid >> 6;
    const int lane = tid & 63;
    const int m16  = lane & 15;
    const int quad = lane >> 4;
    const int wm   = wave >> 1;
    const int wn   = wave & 1;
    const int i0   = blockIdx.x * 128;
    const int n0   = blockIdx.y * 128;
    const int z    = blockIdx.z;

    const float* __restrict__ A = (z == 0) ? A0 : (z == 1) ? A1 : A2;
    const u16*   __restrict__ B = Wb + (size_t)z * DMODEL * DMODEL;

    f32x4 acc[4][4] = {};

    // A staging: thread -> row ar, 32 consecutive fp32 cols at ac
    const int ar = tid >> 1;
    const int ac = (tid & 1) * 32;
    // B staging (per wave, 32 rows, 4 insts of 8 rows): lane -> row l>>3,
    // swizzled chunk (l&7)^((l>>3)&7) of the 128-B row segment
    const int brow   = lane >> 3;
    const int bchunk = (lane & 7) ^ (brow & 7);

    for (int kt = 0; kt < DMODEL; kt += 64) {
        // global A -> regs (fp32), issued before the barrier
        float4 av[8];
        const float4* ap = (const float4*)(A + (size_t)(i0 + ar) * DMODEL + kt + ac);
#pragma unroll
        for (int j = 0; j < 8; j++) av[j] = ap[j];

        __syncthreads();   // all waves done reading previous tiles

        // B -> LDS via global_load_lds (16 B/lane), swizzle in global addr
        {
            const u16* bp = B + ((size_t)(n0 + wave * 32 + brow) * DMODEL + kt) + bchunk * 8;
            u16* lp = &Blds[(wave * 32) * 64];
#pragma unroll
            for (int j = 0; j < 4; j++)
                gl_lds16(bp + (size_t)j * 8 * DMODEL, lp + j * 8 * 64);
        }

        // convert A fp32 -> bf16, ds_write (padded stride 72)
#pragma unroll
        for (int g = 0; g < 4; g++) {
            short8 sv;
            const float4 x0 = av[2 * g], x1 = av[2 * g + 1];
            sv[0] = (short)f2bf(x0.x); sv[1] = (short)f2bf(x0.y);
            sv[2] = (short)f2bf(x0.z); sv[3] = (short)f2bf(x0.w);
            sv[4] = (short)f2bf(x1.x); sv[5] = (short)f2bf(x1.y);
            sv[6] = (short)f2bf(x1.z); sv[7] = (short)f2bf(x1.w);
            *(short8*)&Alds[ar * 72 + ac + g * 8] = sv;
        }

        __syncthreads();   // drains vmcnt (B in LDS) + lgkm (A in LDS)

#pragma unroll
        for (int half = 0; half < 2; half++) {
            short8 af[4], bfr[4];
#pragma unroll
            for (int mt = 0; mt < 4; mt++)
                af[mt] = *(const short8*)&Alds[(wm * 64 + mt * 16 + m16) * 72 + half * 32 + quad * 8];
#pragma unroll
            for (int nt = 0; nt < 4; nt++)
                bfr[nt] = *(const short8*)&Blds[(wn * 64 + nt * 16 + m16) * 64 +
                                                (((half << 2) + quad) ^ (m16 & 7)) * 8];
#pragma unroll
            for (int mt = 0; mt < 4; mt++)
#pragma unroll
                for (int nt = 0; nt < 4; nt++)
                    acc[mt][nt] = __builtin_amdgcn_mfma_f32_16x16x32_bf16(af[mt], bfr[nt], acc[mt][nt], 0, 0, 0);
        }
    }

    if (NORM) {
        // per-head L2 norm: wave's 64-col span == one head
        const int h = (n0 >> 6) + wn;
        u16* outZ = outN + (size_t)z * BATCH * NHEAD * S_LEN * KHD;
#pragma unroll
        for (int mt = 0; mt < 4; mt++) {
#pragma unroll
            for (int r = 0; r < 4; r++) {
                float ss = 0.0f;
#pragma unroll
                for (int nt = 0; nt < 4; nt++) ss += acc[mt][nt][r] * acc[mt][nt][r];
                ss += __shfl_xor(ss, 1);
                ss += __shfl_xor(ss, 2);
                ss += __shfl_xor(ss, 4);
                ss += __shfl_xor(ss, 8);
                const float sc = 1.0f / fmaxf(sqrtf(ss), 1e-12f);
                const int i = i0 + wm * 64 + mt * 16 + quad * 4 + r;
                const int s = i >> 4, b = i & 15;
                u16* op = outZ + (((size_t)b * NHEAD + h) * S_LEN + s) * KHD;
#pragma unroll
                for (int nt = 0; nt < 4; nt++)
                    op[nt * 16 + m16] = f2bf(acc[mt][nt][r] * sc);
            }
        }
    } else {
#pragma unroll
        for (int mt = 0; mt < 4; mt++) {
#pragma unroll
            for (int r = 0; r < 4; r++) {
                const int i = i0 + wm * 64 + mt * 16 + quad * 4 + r;
                float* op = outP + (size_t)i * DMODEL + n0 + wn * 64;
#pragma unroll
                for (int nt = 0; nt < 4; nt++)
                    op[nt * 16 + m16] = acc[mt][nt][r];
            }
        }
    }
}

// ---------------------------------------------------------------------------
// Flash attention (unchanged from round 1): per (b,h), 64 q-rows per block,
// 32-key tiles, bf16 MFMA; writes fp32 concat [S][B][512] into d_out.
// ---------------------------------------------------------------------------
__global__ __launch_bounds__(256) void attn_kernel(
    const u16* __restrict__ wq, const u16* __restrict__ wk, const u16* __restrict__ wv,
    float* __restrict__ concat)
{
    __shared__ __align__(16) u16 Klds[32 * 72];
    __shared__ __align__(16) u16 VTlds[64 * 40];
    __shared__ __align__(16) u16 Plds[4][16 * 40];

    const int tid  = threadIdx.x;
    const int wave = tid >> 6;
    const int lane = tid & 63;
    const int m16  = lane & 15;
    const int quad = lane >> 4;
    const int qt   = blockIdx.x;
    const int bh   = blockIdx.y;

    const u16* Qb = wq + (size_t)bh * S_LEN * KHD;
    const u16* Kb = wk + (size_t)bh * S_LEN * KHD;
    const u16* Vb = wv + (size_t)bh * S_LEN * KHD;

    const int qrow = qt * 64 + wave * 16 + m16;
    const short8 aq0 = *(const short8*)(Qb + (size_t)qrow * KHD + quad * 8);
    const short8 aq1 = *(const short8*)(Qb + (size_t)qrow * KHD + 32 + quad * 8);

    f32x4 o[4] = {};
    float mold[4] = {-1e30f, -1e30f, -1e30f, -1e30f};
    float lsum[4] = {0.0f, 0.0f, 0.0f, 0.0f};
    const float iscale = 0.125f;
    const float LOG2E  = 1.4426950408889634f;

    for (int it = 0; it < S_LEN / 32; it++) {
        const int kt0 = it * 32;
        __syncthreads();
        {
            const int row = tid >> 3;
            const int c8  = (tid & 7) * 8;
            const short8 kv = *(const short8*)(Kb + (size_t)(kt0 + row) * KHD + c8);
            *(short8*)&Klds[row * 72 + c8] = kv;
            const short8 vv = *(const short8*)(Vb + (size_t)(kt0 + row) * KHD + c8);
#pragma unroll
            for (int u = 0; u < 8; u++) VTlds[(c8 + u) * 40 + row] = (u16)vv[u];
        }
        __syncthreads();

        f32x4 sc[2];
#pragma unroll
        for (int nt = 0; nt < 2; nt++) {
            const short8 b0 = *(const short8*)&Klds[(nt * 16 + m16) * 72 + quad * 8];
            const short8 b1 = *(const short8*)&Klds[(nt * 16 + m16) * 72 + 32 + quad * 8];
            f32x4 c = {};
            c = __builtin_amdgcn_mfma_f32_16x16x32_bf16(aq0, b0, c, 0, 0, 0);
            c = __builtin_amdgcn_mfma_f32_16x16x32_bf16(aq1, b1, c, 0, 0, 0);
            sc[nt] = c;
        }

        float alpha[4];
#pragma unroll
        for (int r = 0; r < 4; r++) {
            const float s0v = sc[0][r] * iscale;
            const float s1v = sc[1][r] * iscale;
            float mxr = fmaxf(s0v, s1v);
            mxr = fmaxf(mxr, __shfl_xor(mxr, 1));
            mxr = fmaxf(mxr, __shfl_xor(mxr, 2));
            mxr = fmaxf(mxr, __shfl_xor(mxr, 4));
            mxr = fmaxf(mxr, __shfl_xor(mxr, 8));
            const float mnew = fmaxf(mold[r], mxr);
            alpha[r] = exp2f((mold[r] - mnew) * LOG2E);
            const float p0 = exp2f((s0v - mnew) * LOG2E);
            const float p1 = exp2f((s1v - mnew) * LOG2E);
            float rs = p0 + p1;
            rs += __shfl_xor(rs, 1);
            rs += __shfl_xor(rs, 2);
            rs += __shfl_xor(rs, 4);
            rs += __shfl_xor(rs, 8);
            lsum[r] = lsum[r] * alpha[r] + rs;
            mold[r] = mnew;
            Plds[wave][(quad * 4 + r) * 40 + m16]      = f2bf(p0);
            Plds[wave][(quad * 4 + r) * 40 + 16 + m16] = f2bf(p1);
        }
        __syncthreads();

        const short8 pa = *(const short8*)&Plds[wave][m16 * 40 + quad * 8];
#pragma unroll
        for (int nt2 = 0; nt2 < 4; nt2++) {
            const short8 vb = *(const short8*)&VTlds[(nt2 * 16 + m16) * 40 + quad * 8];
#pragma unroll
            for (int r = 0; r < 4; r++) o[nt2][r] *= alpha[r];
            o[nt2] = __builtin_amdgcn_mfma_f32_16x16x32_bf16(pa, vb, o[nt2], 0, 0, 0);
        }
    }

    const int b = bh >> 3, h = bh & 7;
#pragma unroll
    for (int r = 0; r < 4; r++) {
        const float inv = 1.0f / lsum[r];
        const int row = qt * 64 + wave * 16 + quad * 4 + r;
        float* cp = concat + ((size_t)row * BATCH + b) * (NHEAD * KHD) + h * KHD;
#pragma unroll
        for (int nt2 = 0; nt2 < 4; nt2++)
            cp[nt2 * 16 + m16] = o[nt2][r] * inv;
    }
}

extern "C" void kernel_launch(void* const* d_in, const int* in_sizes, int n_in,
                              void* d_out, int out_size, void* d_ws, size_t ws_size,
                              hipStream_t stream) {
    const float* q    = (const float*)d_in[0];
    const float* k    = (const float*)d_in[1];
    const float* v    = (const float*)d_in[2];
    const float* WQ   = (const float*)d_in[3];
    const float* WK   = (const float*)d_in[4];
    const float* WV   = (const float*)d_in[5];
    const float* Wout = (const float*)d_in[6];
    float* out = (float*)d_out;

    // ws layout: [3][B*H*S*64] bf16 normalized q/k/v (50.3 MB), then
    // [4][512*512] bf16 weights (2 MB). Total 52.4 MB.
    const size_t per = (size_t)BATCH * NHEAD * S_LEN * KHD;
    u16* wsQKV = (u16*)d_ws;
    u16* wsW   = wsQKV + 3 * per;

    // 1. weights fp32 -> bf16
    wcvt_kernel<<<dim3(256, 4), 256, 0, stream>>>(WQ, WK, WV, Wout, wsW);

    // 2. projections + per-head L2 norm (bf16 MFMA GEMM)
    gemm_kernel<1><<<dim3(NROW / 128, DMODEL / 128, 3), 256, 0, stream>>>(
        q, k, v, wsW, wsQKV, nullptr);

    // 3. attention -> fp32 concat in d_out
    attn_kernel<<<dim3(S_LEN / 64, BATCH * NHEAD), 256, 0, stream>>>(
        wsQKV, wsQKV + per, wsQKV + 2 * per, out);

    // 4. output projection, in-place on d_out (A = concat fp32, B = Wout bf16)
    gemm_kernel<0><<<dim3(NROW / 128, DMODEL / 128, 1), 256, 0, stream>>>(
        out, nullptr, nullptr, wsW + (size_t)3 * DMODEL * DMODEL, nullptr, out);
}

// Round 3
// 298.153 us; speedup vs baseline: 3.1109x; 1.4441x over previous
//
#include <hip/hip_runtime.h>
#include <cstdint>
#include <cstddef>

typedef unsigned int u32;
typedef unsigned short u16;
typedef __attribute__((ext_vector_type(8))) short short8;   // 8 bf16 = 4 VGPRs (MFMA A/B frag)
typedef __attribute__((ext_vector_type(4))) float f32x4;    // MFMA C/D frag

#define S_LEN 1024
#define BATCH 16
#define NHEAD 8
#define DMODEL 512
#define KHD 64
#define NROW (S_LEN * BATCH)          // 16384 GEMM rows

__device__ __forceinline__ u16 f2bf(float f) {
    u32 u = __float_as_uint(f);
    return (u16)((u + 0x7fffu + ((u >> 16) & 1u)) >> 16);   // RTNE
}

__device__ __forceinline__ void gl_lds16(const void* g, void* l) {
    __builtin_amdgcn_global_load_lds(
        (const __attribute__((address_space(1))) void*)(uintptr_t)g,
        (__attribute__((address_space(3))) void*)(uintptr_t)l, 16, 0, 0);
}

// ---------------------------------------------------------------------------
// Convert the 4 weight matrices (512x512 fp32) to bf16, packed [4][512*512].
// ---------------------------------------------------------------------------
__global__ __launch_bounds__(256) void wcvt_kernel(
    const float* __restrict__ WQ, const float* __restrict__ WK,
    const float* __restrict__ WV, const float* __restrict__ Wo,
    u16* __restrict__ dst)
{
    const int m = blockIdx.y;
    const float* __restrict__ src = (m == 0) ? WQ : (m == 1) ? WK : (m == 2) ? WV : Wo;
    const int idx = (blockIdx.x * 256 + threadIdx.x) * 4;
    const float4 v = *(const float4*)(src + idx);
    u16 r[4];
    r[0] = f2bf(v.x); r[1] = f2bf(v.y); r[2] = f2bf(v.z); r[3] = f2bf(v.w);
    *(uint2*)(dst + (size_t)m * DMODEL * DMODEL + idx) = *(uint2*)r;
}

// ---------------------------------------------------------------------------
// bf16-MFMA GEMM, 128x128 tile, BK=64, out[i][n] = sum_d A[i][d] * B[n][d].
// M==0: plain fp32 out to outP (in-place safe).          grid (128,4,1)
// M==1: per-head L2 norm, bf16 out [B][H][S][64], z=q/k. grid (128,4,2)
// M==2: per-head L2 norm, V TRANSPOSED out [B][H][64][S].grid (8,4,16)
//       (rows of the i-tile are 128 consecutive s for one batch bb, so the
//        4 accumulator regs r=0..3 are consecutive s -> b64 packed writes)
// ---------------------------------------------------------------------------
template<int M>
__global__ __launch_bounds__(256) void gemm_kernel(
    const float* __restrict__ A0, const float* __restrict__ A1,
    const u16* __restrict__ Wb,     // bf16 weights (M==1: +z*512*512)
    u16* __restrict__ outN,         // M==1: [2][B][H][S][64]; M==2: wvT base
    float* __restrict__ outP)       // M==0: [16384][512]
{
    __shared__ __align__(16) u16 Alds[128 * 72];
    __shared__ __align__(16) u16 Blds[128 * 64];

    const int tid  = threadIdx.x;
    const int wave = tid >> 6;
    const int lane = tid & 63;
    const int m16  = lane & 15;
    const int quad = lane >> 4;
    const int wm   = wave >> 1;
    const int wn   = wave & 1;
    const int n0   = blockIdx.y * 128;
    const int i0   = (M == 2) ? 0 : blockIdx.x * 128;
    const int s0   = (M == 2) ? blockIdx.x * 128 : 0;
    const int bb   = (M == 2) ? blockIdx.z : 0;
    const int z    = (M == 1) ? blockIdx.z : 0;

    const float* __restrict__ A = (M == 1 && z == 1) ? A1 : A0;
    const u16*   __restrict__ B = Wb + ((M == 1) ? (size_t)z * DMODEL * DMODEL : 0);

    f32x4 acc[4][4] = {};

    const int ar = tid >> 1;           // A staging row (tile-local)
    const int ac = (tid & 1) * 32;     // 32 fp32 cols
    const int brow   = lane >> 3;
    const int bchunk = (lane & 7) ^ (brow & 7);

    for (int kt = 0; kt < DMODEL; kt += 64) {
        float4 av[8];
        const size_t aoff = (M == 2) ? (((size_t)(s0 + ar) * BATCH + bb) * DMODEL)
                                     : ((size_t)(i0 + ar) * DMODEL);
        const float4* ap = (const float4*)(A + aoff + kt + ac);
#pragma unroll
        for (int j = 0; j < 8; j++) av[j] = ap[j];

        __syncthreads();

        {
            const u16* bp = B + ((size_t)(n0 + wave * 32 + brow) * DMODEL + kt) + bchunk * 8;
            u16* lp = &Blds[(wave * 32) * 64];
#pragma unroll
            for (int j = 0; j < 4; j++)
                gl_lds16(bp + (size_t)j * 8 * DMODEL, lp + j * 8 * 64);
        }

#pragma unroll
        for (int g = 0; g < 4; g++) {
            short8 sv;
            const float4 x0 = av[2 * g], x1 = av[2 * g + 1];
            sv[0] = (short)f2bf(x0.x); sv[1] = (short)f2bf(x0.y);
            sv[2] = (short)f2bf(x0.z); sv[3] = (short)f2bf(x0.w);
            sv[4] = (short)f2bf(x1.x); sv[5] = (short)f2bf(x1.y);
            sv[6] = (short)f2bf(x1.z); sv[7] = (short)f2bf(x1.w);
            *(short8*)&Alds[ar * 72 + ac + g * 8] = sv;
        }

        __syncthreads();

#pragma unroll
        for (int half = 0; half < 2; half++) {
            short8 af[4], bfr[4];
#pragma unroll
            for (int mt = 0; mt < 4; mt++)
                af[mt] = *(const short8*)&Alds[(wm * 64 + mt * 16 + m16) * 72 + half * 32 + quad * 8];
#pragma unroll
            for (int nt = 0; nt < 4; nt++)
                bfr[nt] = *(const short8*)&Blds[(wn * 64 + nt * 16 + m16) * 64 +
                                                (((half << 2) + quad) ^ (m16 & 7)) * 8];
#pragma unroll
            for (int mt = 0; mt < 4; mt++)
#pragma unroll
                for (int nt = 0; nt < 4; nt++)
                    acc[mt][nt] = __builtin_amdgcn_mfma_f32_16x16x32_bf16(af[mt], bfr[nt], acc[mt][nt], 0, 0, 0);
        }
    }

    if (M == 1) {
        const int h = (n0 >> 6) + wn;
        u16* outZ = outN + (size_t)z * BATCH * NHEAD * S_LEN * KHD;
#pragma unroll
        for (int mt = 0; mt < 4; mt++) {
#pragma unroll
            for (int r = 0; r < 4; r++) {
                float ss = 0.0f;
#pragma unroll
                for (int nt = 0; nt < 4; nt++) ss += acc[mt][nt][r] * acc[mt][nt][r];
                ss += __shfl_xor(ss, 1);
                ss += __shfl_xor(ss, 2);
                ss += __shfl_xor(ss, 4);
                ss += __shfl_xor(ss, 8);
                const float sc = 1.0f / fmaxf(sqrtf(ss), 1e-12f);
                const int i = i0 + wm * 64 + mt * 16 + quad * 4 + r;
                const int s = i >> 4, b = i & 15;
                u16* op = outZ + (((size_t)b * NHEAD + h) * S_LEN + s) * KHD;
#pragma unroll
                for (int nt = 0; nt < 4; nt++)
                    op[nt * 16 + m16] = f2bf(acc[mt][nt][r] * sc);
            }
        }
    } else if (M == 2) {
        // rows = consecutive s (batch bb fixed); write wvT[bb][h][vcol][s]
        const int h = (n0 >> 6) + wn;
#pragma unroll
        for (int mt = 0; mt < 4; mt++) {
            float scl[4];
#pragma unroll
            for (int r = 0; r < 4; r++) {
                float ss = 0.0f;
#pragma unroll
                for (int nt = 0; nt < 4; nt++) ss += acc[mt][nt][r] * acc[mt][nt][r];
                ss += __shfl_xor(ss, 1);
                ss += __shfl_xor(ss, 2);
                ss += __shfl_xor(ss, 4);
                ss += __shfl_xor(ss, 8);
                scl[r] = 1.0f / fmaxf(sqrtf(ss), 1e-12f);
            }
            const int sbase = s0 + wm * 64 + mt * 16 + quad * 4;
#pragma unroll
            for (int nt = 0; nt < 4; nt++) {
                const int vcol = nt * 16 + m16;
                const u32 lo = (u32)f2bf(acc[mt][nt][0] * scl[0]) |
                               ((u32)f2bf(acc[mt][nt][1] * scl[1]) << 16);
                const u32 hi = (u32)f2bf(acc[mt][nt][2] * scl[2]) |
                               ((u32)f2bf(acc[mt][nt][3] * scl[3]) << 16);
                uint2 pk; pk.x = lo; pk.y = hi;
                u16* dp = outN + (((size_t)bb * NHEAD + h) * KHD + vcol) * S_LEN + sbase;
                *(uint2*)dp = pk;
            }
        }
    } else {
#pragma unroll
        for (int mt = 0; mt < 4; mt++) {
#pragma unroll
            for (int r = 0; r < 4; r++) {
                const int i = i0 + wm * 64 + mt * 16 + quad * 4 + r;
                float* op = outP + (size_t)i * DMODEL + n0 + wn * 64;
#pragma unroll
                for (int nt = 0; nt < 4; nt++)
                    op[nt * 16 + m16] = acc[mt][nt][r];
            }
        }
    }
}

// ---------------------------------------------------------------------------
// Attention v2. Scores are cosine/8 in [-0.125,0.125] -> NO online softmax:
// p = exp2(s*log2e/8) directly, per-lane partial row-sums, single final
// reduction. S^T = K*Q^T orientation (swap MFMA operands, free) so P exits
// with 4 consecutive keys per reg -> b64 wave-private LDS round-trip, no
// extra barrier. V^T comes pre-transposed from global ([b][h][vcol][s]).
// Block: 128 q rows, 4 waves x 32 q (2 qsets), 64-key iterations.
// ---------------------------------------------------------------------------
__global__ __launch_bounds__(256) void attn_kernel(
    const u16* __restrict__ wq, const u16* __restrict__ wk, const u16* __restrict__ wvT,
    float* __restrict__ concat)
{
    __shared__ __align__(16) u16 Klds[64 * 64];       // [key][dim], XOR-swizzled chunks
    __shared__ __align__(16) u16 Vlds[64 * 64];       // [vcol][key], XOR-swizzled chunks
    __shared__ __align__(16) u16 Plds[4][2][16 * 72]; // per-wave per-qset [q16][key72]

    const int tid  = threadIdx.x;
    const int wave = tid >> 6;
    const int lane = tid & 63;
    const int m16  = lane & 15;
    const int quad = lane >> 4;
    const int qt   = blockIdx.x;        // 8 tiles of 128 q
    const int bh   = blockIdx.y;        // 0..127

    const u16* Qb = wq  + (size_t)bh * S_LEN * KHD;
    const u16* Kb = wk  + (size_t)bh * S_LEN * KHD;
    const u16* Vb = wvT + (size_t)bh * KHD * S_LEN;

    // persistent Q B-frags: q = qt*128 + wave*32 + qs*16 + m16
    short8 qf[2][2];
#pragma unroll
    for (int qs = 0; qs < 2; qs++) {
        const int qrow = qt * 128 + wave * 32 + qs * 16 + m16;
#pragma unroll
        for (int hf = 0; hf < 2; hf++)
            qf[qs][hf] = *(const short8*)(Qb + (size_t)qrow * KHD + hf * 32 + quad * 8);
    }

    f32x4 o[2][4] = {};                 // D[m=vcol][n=q]
    float lsum[2] = {0.0f, 0.0f};
    const float SC8 = 0.18033688011112042f;   // log2(e)/8

    const int srow   = lane >> 3;               // 0..7
    const int schunk = (lane & 7) ^ srow;       // XOR chunk swizzle

    for (int it = 0; it < S_LEN / 64; it++) {
        const int kt0 = it * 64;
        __syncthreads();   // all waves done with previous K/V tiles
        {
            const int r0 = wave * 8 + srow;
            gl_lds16(Kb + (size_t)(kt0 + r0) * KHD + schunk * 8,        &Klds[(wave * 8) * 64]);
            gl_lds16(Kb + (size_t)(kt0 + r0 + 32) * KHD + schunk * 8,   &Klds[(wave * 8 + 32) * 64]);
            gl_lds16(Vb + (size_t)r0 * S_LEN + kt0 + schunk * 8,        &Vlds[(wave * 8) * 64]);
            gl_lds16(Vb + (size_t)(r0 + 32) * S_LEN + kt0 + schunk * 8, &Vlds[(wave * 8 + 32) * 64]);
        }
        __syncthreads();   // drain vmcnt: K/V visible

        // S^T tiles: D[m=key][n=q] = K-frag x Q-frag
        f32x4 sc[2][4];
#pragma unroll
        for (int mt = 0; mt < 4; mt++) {
            short8 kf0 = *(const short8*)&Klds[(mt * 16 + m16) * 64 + ((quad) ^ (m16 & 7)) * 8];
            short8 kf1 = *(const short8*)&Klds[(mt * 16 + m16) * 64 + ((4 + quad) ^ (m16 & 7)) * 8];
#pragma unroll
            for (int qs = 0; qs < 2; qs++) {
                f32x4 c = {};
                c = __builtin_amdgcn_mfma_f32_16x16x32_bf16(kf0, qf[qs][0], c, 0, 0, 0);
                c = __builtin_amdgcn_mfma_f32_16x16x32_bf16(kf1, qf[qs][1], c, 0, 0, 0);
                sc[qs][mt] = c;
            }
        }

        // exp (no max subtraction needed) + b64 P write + per-lane partial sums
#pragma unroll
        for (int qs = 0; qs < 2; qs++) {
#pragma unroll
            for (int mt = 0; mt < 4; mt++) {
                const float p0 = exp2f(sc[qs][mt][0] * SC8);
                const float p1 = exp2f(sc[qs][mt][1] * SC8);
                const float p2 = exp2f(sc[qs][mt][2] * SC8);
                const float p3 = exp2f(sc[qs][mt][3] * SC8);
                lsum[qs] += (p0 + p1) + (p2 + p3);
                uint2 pk;
                pk.x = (u32)f2bf(p0) | ((u32)f2bf(p1) << 16);
                pk.y = (u32)f2bf(p2) | ((u32)f2bf(p3) << 16);
                *(uint2*)&Plds[wave][qs][m16 * 72 + mt * 16 + quad * 4] = pk;
            }
        }

        // PV: D[m=vcol][n=q] += V^T-frag x P-frag   (wave-private, no barrier)
#pragma unroll
        for (int c = 0; c < 2; c++) {
            short8 pb[2];
#pragma unroll
            for (int qs = 0; qs < 2; qs++)
                pb[qs] = *(const short8*)&Plds[wave][qs][m16 * 72 + c * 32 + quad * 8];
#pragma unroll
            for (int vt = 0; vt < 4; vt++) {
                const short8 vf = *(const short8*)&Vlds[(vt * 16 + m16) * 64 +
                                                        (((c << 2) + quad) ^ (m16 & 7)) * 8];
#pragma unroll
                for (int qs = 0; qs < 2; qs++)
                    o[qs][vt] = __builtin_amdgcn_mfma_f32_16x16x32_bf16(vf, pb[qs], o[qs][vt], 0, 0, 0);
            }
        }
    }

    // final row-sum reduction across quads (lane's q is fixed = qs*16+m16)
#pragma unroll
    for (int qs = 0; qs < 2; qs++) {
        lsum[qs] += __shfl_xor(lsum[qs], 16);
        lsum[qs] += __shfl_xor(lsum[qs], 32);
    }

    const int b = bh >> 3, h = bh & 7;
#pragma unroll
    for (int qs = 0; qs < 2; qs++) {
        const float inv = 1.0f / lsum[qs];
        const int qrow = qt * 128 + wave * 32 + qs * 16 + m16;
        float* cp = concat + ((size_t)qrow * BATCH + b) * (NHEAD * KHD) + h * KHD;
#pragma unroll
        for (int vt = 0; vt < 4; vt++) {
            float4 v4;
            v4.x = o[qs][vt][0] * inv;
            v4.y = o[qs][vt][1] * inv;
            v4.z = o[qs][vt][2] * inv;
            v4.w = o[qs][vt][3] * inv;
            *(float4*)(cp + vt * 16 + quad * 4) = v4;
        }
    }
}

extern "C" void kernel_launch(void* const* d_in, const int* in_sizes, int n_in,
                              void* d_out, int out_size, void* d_ws, size_t ws_size,
                              hipStream_t stream) {
    const float* q    = (const float*)d_in[0];
    const float* k    = (const float*)d_in[1];
    const float* v    = (const float*)d_in[2];
    const float* WQ   = (const float*)d_in[3];
    const float* WK   = (const float*)d_in[4];
    const float* WV   = (const float*)d_in[5];
    const float* Wout = (const float*)d_in[6];
    float* out = (float*)d_out;

    // ws layout: [3][B*H*S*64] bf16 (wq, wk, wvT) 50.3 MB + [4][512*512] bf16
    // weights 2 MB = 52.4 MB total.
    const size_t per = (size_t)BATCH * NHEAD * S_LEN * KHD;
    u16* wsQKV = (u16*)d_ws;
    u16* wsW   = wsQKV + 3 * per;

    wcvt_kernel<<<dim3(256, 4), 256, 0, stream>>>(WQ, WK, WV, Wout, wsW);

    // q,k projections + norm -> [B][H][S][64]
    gemm_kernel<1><<<dim3(NROW / 128, DMODEL / 128, 2), 256, 0, stream>>>(
        q, k, wsW, wsQKV, nullptr);

    // v projection + norm -> TRANSPOSED [B][H][64][S]
    gemm_kernel<2><<<dim3(S_LEN / 128, DMODEL / 128, BATCH), 256, 0, stream>>>(
        v, nullptr, wsW + (size_t)2 * DMODEL * DMODEL, wsQKV + 2 * per, nullptr);

    // attention -> fp32 concat in d_out
    attn_kernel<<<dim3(S_LEN / 128, BATCH * NHEAD), 256, 0, stream>>>(
        wsQKV, wsQKV + per, wsQKV + 2 * per, out);

    // output projection, in-place on d_out
    gemm_kernel<0><<<dim3(NROW / 128, DMODEL / 128, 1), 256, 0, stream>>>(
        out, nullptr, wsW + (size_t)3 * DMODEL * DMODEL, nullptr, out);
}

// Round 4
// 283.362 us; speedup vs baseline: 3.2732x; 1.0522x over previous
//
#include <hip/hip_runtime.h>
#include <cstdint>
#include <cstddef>

typedef unsigned int u32;
typedef unsigned short u16;
typedef __attribute__((ext_vector_type(8))) short short8;   // 8 bf16 = 4 VGPRs (MFMA A/B frag)
typedef __attribute__((ext_vector_type(4))) float f32x4;    // MFMA C/D frag

#define S_LEN 1024
#define BATCH 16
#define NHEAD 8
#define DMODEL 512
#define KHD 64
#define NROW (S_LEN * BATCH)          // 16384 GEMM rows

__device__ __forceinline__ u16 f2bf(float f) {
    u32 u = __float_as_uint(f);
    return (u16)((u + 0x7fffu + ((u >> 16) & 1u)) >> 16);   // RTNE
}

__device__ __forceinline__ void gl_lds16(const void* g, void* l) {
    __builtin_amdgcn_global_load_lds(
        (const __attribute__((address_space(1))) void*)(uintptr_t)g,
        (__attribute__((address_space(3))) void*)(uintptr_t)l, 16, 0, 0);
}

// ---------------------------------------------------------------------------
// Weights fp32 -> bf16, packed [4][512*512] into ws.
// ---------------------------------------------------------------------------
__global__ __launch_bounds__(256) void wcvt_kernel(
    const float* __restrict__ WQ, const float* __restrict__ WK,
    const float* __restrict__ WV, const float* __restrict__ Wo,
    u16* __restrict__ dst)
{
    const int m = blockIdx.y;
    const float* __restrict__ src = (m == 0) ? WQ : (m == 1) ? WK : (m == 2) ? WV : Wo;
    const int idx = (blockIdx.x * 256 + threadIdx.x) * 4;
    const float4 v = *(const float4*)(src + idx);
    u16 r[4];
    r[0] = f2bf(v.x); r[1] = f2bf(v.y); r[2] = f2bf(v.z); r[3] = f2bf(v.w);
    *(uint2*)(dst + (size_t)m * DMODEL * DMODEL + idx) = *(uint2*)r;
}

// ---------------------------------------------------------------------------
// Activation fp32 -> bf16 (layout-preserving). blockIdx.y picks s0/s1 and the
// destination half (dst + y*NROW*DMODEL).
// ---------------------------------------------------------------------------
__global__ __launch_bounds__(256) void xcvt_kernel(
    const float* __restrict__ s0, const float* __restrict__ s1,
    u16* __restrict__ dst)
{
    const float* __restrict__ src = (blockIdx.y == 0) ? s0 : s1;
    u16* d = dst + (size_t)blockIdx.y * NROW * DMODEL;
    const int idx = (blockIdx.x * 256 + threadIdx.x) * 4;
    const float4 v = *(const float4*)(src + idx);
    u16 r[4];
    r[0] = f2bf(v.x); r[1] = f2bf(v.y); r[2] = f2bf(v.z); r[3] = f2bf(v.w);
    *(uint2*)(d + idx) = *(uint2*)r;
}

// ---------------------------------------------------------------------------
// bf16-MFMA GEMM, 128x128 tile, BK=64. A and B both staged via
// global_load_lds width=16 with XOR chunk swizzle in the GLOBAL address
// (LDS side lane-contiguous) -> conflict-free b128 frag reads, zero VALU
// conversion in the K-loop.
// M==0: fp32 out to outP.                                 grid (128,4,1)
// M==1: per-head L2 norm, bf16 out [B][H][S][64], z=q/k.  grid (128,4,2)
// M==2: per-head L2 norm, V transposed out [B][H][64][S]. grid (8,4,16)
//       A rows are consecutive s for batch bb (astr = B*D).
// ---------------------------------------------------------------------------
template<int M>
__global__ __launch_bounds__(256) void gemm_kernel(
    const u16* __restrict__ Abf,    // bf16 A base (M1: +z*NROW*D; M2: +bb*D)
    const u16* __restrict__ Wb,     // bf16 weight panel (M1: +z*D*D inside)
    u16* __restrict__ outN,
    float* __restrict__ outP)
{
    __shared__ __align__(16) u16 Alds[128 * 64];
    __shared__ __align__(16) u16 Blds[128 * 64];

    const int tid  = threadIdx.x;
    const int wave = tid >> 6;
    const int lane = tid & 63;
    const int m16  = lane & 15;
    const int quad = lane >> 4;
    const int wm   = wave >> 1;
    const int wn   = wave & 1;
    const int n0   = blockIdx.y * 128;
    const int row0 = blockIdx.x * 128;
    const int z    = (M == 1) ? blockIdx.z : 0;
    const int bb   = (M == 2) ? blockIdx.z : 0;

    const u16* __restrict__ A = Abf + (size_t)z * NROW * DMODEL + (size_t)bb * DMODEL;
    const size_t astr = (M == 2) ? (size_t)BATCH * DMODEL : (size_t)DMODEL;
    const u16* __restrict__ B = Wb + ((M == 1) ? (size_t)z * DMODEL * DMODEL : 0);

    f32x4 acc[4][4] = {};

    const int brow   = lane >> 3;              // 0..7
    const int bchunk = (lane & 7) ^ brow;      // XOR chunk swizzle

    for (int kt = 0; kt < DMODEL; kt += 64) {
        __syncthreads();   // previous-iteration frag reads done
        {
            const u16* ap = A + (size_t)(row0 + wave * 32 + brow) * astr + kt + bchunk * 8;
            const u16* bp = B + (size_t)(n0 + wave * 32 + brow) * DMODEL + kt + bchunk * 8;
            u16* la = &Alds[(wave * 32) * 64];
            u16* lb = &Blds[(wave * 32) * 64];
#pragma unroll
            for (int j = 0; j < 4; j++) {
                gl_lds16(ap + (size_t)j * 8 * astr,   la + j * 8 * 64);
                gl_lds16(bp + (size_t)j * 8 * DMODEL, lb + j * 8 * 64);
            }
        }
        __syncthreads();   // drains vmcnt: tiles visible

#pragma unroll
        for (int half = 0; half < 2; half++) {
            short8 af[4], bfr[4];
#pragma unroll
            for (int mt = 0; mt < 4; mt++)
                af[mt] = *(const short8*)&Alds[(wm * 64 + mt * 16 + m16) * 64 +
                                               (((half << 2) + quad) ^ (m16 & 7)) * 8];
#pragma unroll
            for (int nt = 0; nt < 4; nt++)
                bfr[nt] = *(const short8*)&Blds[(wn * 64 + nt * 16 + m16) * 64 +
                                                (((half << 2) + quad) ^ (m16 & 7)) * 8];
#pragma unroll
            for (int mt = 0; mt < 4; mt++)
#pragma unroll
                for (int nt = 0; nt < 4; nt++)
                    acc[mt][nt] = __builtin_amdgcn_mfma_f32_16x16x32_bf16(af[mt], bfr[nt], acc[mt][nt], 0, 0, 0);
        }
    }

    if (M == 1) {
        const int h = (n0 >> 6) + wn;
        u16* outZ = outN + (size_t)z * BATCH * NHEAD * S_LEN * KHD;
#pragma unroll
        for (int mt = 0; mt < 4; mt++) {
#pragma unroll
            for (int r = 0; r < 4; r++) {
                float ss = 0.0f;
#pragma unroll
                for (int nt = 0; nt < 4; nt++) ss += acc[mt][nt][r] * acc[mt][nt][r];
                ss += __shfl_xor(ss, 1);
                ss += __shfl_xor(ss, 2);
                ss += __shfl_xor(ss, 4);
                ss += __shfl_xor(ss, 8);
                const float sc = 1.0f / fmaxf(sqrtf(ss), 1e-12f);
                const int i = row0 + wm * 64 + mt * 16 + quad * 4 + r;
                const int s = i >> 4, b = i & 15;
                u16* op = outZ + (((size_t)b * NHEAD + h) * S_LEN + s) * KHD;
#pragma unroll
                for (int nt = 0; nt < 4; nt++)
                    op[nt * 16 + m16] = f2bf(acc[mt][nt][r] * sc);
            }
        }
    } else if (M == 2) {
        const int h = (n0 >> 6) + wn;
#pragma unroll
        for (int mt = 0; mt < 4; mt++) {
            float scl[4];
#pragma unroll
            for (int r = 0; r < 4; r++) {
                float ss = 0.0f;
#pragma unroll
                for (int nt = 0; nt < 4; nt++) ss += acc[mt][nt][r] * acc[mt][nt][r];
                ss += __shfl_xor(ss, 1);
                ss += __shfl_xor(ss, 2);
                ss += __shfl_xor(ss, 4);
                ss += __shfl_xor(ss, 8);
                scl[r] = 1.0f / fmaxf(sqrtf(ss), 1e-12f);
            }
            const int sbase = row0 + wm * 64 + mt * 16 + quad * 4;
#pragma unroll
            for (int nt = 0; nt < 4; nt++) {
                const int vcol = nt * 16 + m16;
                uint2 pk;
                pk.x = (u32)f2bf(acc[mt][nt][0] * scl[0]) |
                       ((u32)f2bf(acc[mt][nt][1] * scl[1]) << 16);
                pk.y = (u32)f2bf(acc[mt][nt][2] * scl[2]) |
                       ((u32)f2bf(acc[mt][nt][3] * scl[3]) << 16);
                u16* dp = outN + (((size_t)bb * NHEAD + h) * KHD + vcol) * S_LEN + sbase;
                *(uint2*)dp = pk;
            }
        }
    } else {
#pragma unroll
        for (int mt = 0; mt < 4; mt++) {
#pragma unroll
            for (int r = 0; r < 4; r++) {
                const int i = row0 + wm * 64 + mt * 16 + quad * 4 + r;
                float* op = outP + (size_t)i * DMODEL + n0 + wn * 64;
#pragma unroll
                for (int nt = 0; nt < 4; nt++)
                    op[nt * 16 + m16] = acc[mt][nt][r];
            }
        }
    }
}

// ---------------------------------------------------------------------------
// Attention v3. 64 q/block (16 per wave), 64-key iters, grid (16,128).
// Scores = cos/8 in [-0.125,0.125]:
//   p = exp(y/8) via cubic Taylor (3 FMA, err ~1e-5 << bf16 ulp)
//   P packed by TRUNCATION (cheap); row-sum computed by an extra ones-MFMA
//   on the bf16 P itself -> exact num/denom consistency, zero shuffles.
// Output: bf16 concat [S][B][H*K] -> Xc (= d_out scratch).
// ---------------------------------------------------------------------------
__global__ __launch_bounds__(256) void attn_kernel(
    const u16* __restrict__ wq, const u16* __restrict__ wk, const u16* __restrict__ wvT,
    u16* __restrict__ Xc)
{
    __shared__ __align__(16) u16 Klds[64 * 64];       // [key][dim], XOR chunks
    __shared__ __align__(16) u16 Vlds[64 * 64];       // [vcol][key], XOR chunks
    __shared__ __align__(16) u16 Plds[4][16 * 72];    // per-wave [q16][key64], stride 72

    const int tid  = threadIdx.x;
    const int wave = tid >> 6;
    const int lane = tid & 63;
    const int m16  = lane & 15;
    const int quad = lane >> 4;
    const int qt   = blockIdx.x;        // 16 tiles of 64 q
    const int bh   = blockIdx.y;        // 0..127

    const u16* Qb = wq  + (size_t)bh * S_LEN * KHD;
    const u16* Kb = wk  + (size_t)bh * S_LEN * KHD;
    const u16* Vb = wvT + (size_t)bh * KHD * S_LEN;

    const int qrow = qt * 64 + wave * 16 + m16;
    const short8 qf0 = *(const short8*)(Qb + (size_t)qrow * KHD + quad * 8);
    const short8 qf1 = *(const short8*)(Qb + (size_t)qrow * KHD + 32 + quad * 8);

    short8 ones;
#pragma unroll
    for (int j = 0; j < 8; j++) ones[j] = (short)0x3F80;   // bf16 1.0

    f32x4 o[4] = {};    // D[m=vcol][n=q]
    f32x4 ls  = {};     // ones-MFMA row-sum accumulator (all regs identical)
    const float C1 = 0.125f, C2 = 0.0078125f, C3 = 3.2552083e-4f;

    const int srow   = lane >> 3;
    const int schunk = (lane & 7) ^ srow;

    for (int it = 0; it < S_LEN / 64; it++) {
        const int kt0 = it * 64;
        __syncthreads();
        {
            const int r0 = wave * 8 + srow;
            gl_lds16(Kb + (size_t)(kt0 + r0) * KHD + schunk * 8,        &Klds[(wave * 8) * 64]);
            gl_lds16(Kb + (size_t)(kt0 + r0 + 32) * KHD + schunk * 8,   &Klds[(wave * 8 + 32) * 64]);
            gl_lds16(Vb + (size_t)r0 * S_LEN + kt0 + schunk * 8,        &Vlds[(wave * 8) * 64]);
            gl_lds16(Vb + (size_t)(r0 + 32) * S_LEN + kt0 + schunk * 8, &Vlds[(wave * 8 + 32) * 64]);
        }
        __syncthreads();

        // S^T: D[m=key][n=q] = K x Q^T; p = exp(y/8) poly; truncate-pack
#pragma unroll
        for (int mt = 0; mt < 4; mt++) {
            const short8 kf0 = *(const short8*)&Klds[(mt * 16 + m16) * 64 + (quad ^ (m16 & 7)) * 8];
            const short8 kf1 = *(const short8*)&Klds[(mt * 16 + m16) * 64 + ((4 + quad) ^ (m16 & 7)) * 8];
            f32x4 c = {};
            c = __builtin_amdgcn_mfma_f32_16x16x32_bf16(kf0, qf0, c, 0, 0, 0);
            c = __builtin_amdgcn_mfma_f32_16x16x32_bf16(kf1, qf1, c, 0, 0, 0);
            u32 up[4];
#pragma unroll
            for (int r = 0; r < 4; r++) {
                const float y = c[r];
                const float p = fmaf(fmaf(fmaf(C3, y, C2), y, C1), y, 1.0f);
                up[r] = __float_as_uint(p);
            }
            uint2 pk;
            pk.x = (up[0] >> 16) | (up[1] & 0xffff0000u);
            pk.y = (up[2] >> 16) | (up[3] & 0xffff0000u);
            *(uint2*)&Plds[wave][m16 * 72 + mt * 16 + quad * 4] = pk;
        }

        // PV + ones-MFMA row-sum (wave-private P, no barrier)
#pragma unroll
        for (int c = 0; c < 2; c++) {
            const short8 pb = *(const short8*)&Plds[wave][m16 * 72 + c * 32 + quad * 8];
            ls = __builtin_amdgcn_mfma_f32_16x16x32_bf16(ones, pb, ls, 0, 0, 0);
#pragma unroll
            for (int vt = 0; vt < 4; vt++) {
                const short8 vf = *(const short8*)&Vlds[(vt * 16 + m16) * 64 +
                                                        (((c << 2) + quad) ^ (m16 & 7)) * 8];
                o[vt] = __builtin_amdgcn_mfma_f32_16x16x32_bf16(vf, pb, o[vt], 0, 0, 0);
            }
        }
    }

    // epilogue: lane's q = m16 (all ls regs hold that q's row-sum)
    const float inv = 1.0f / ls[0];
    const int b = bh >> 3, h = bh & 7;
    u16* cp = Xc + ((size_t)qrow * BATCH + b) * (NHEAD * KHD) + h * KHD;
#pragma unroll
    for (int vt = 0; vt < 4; vt++) {
        uint2 pk;
        pk.x = (u32)f2bf(o[vt][0] * inv) | ((u32)f2bf(o[vt][1] * inv) << 16);
        pk.y = (u32)f2bf(o[vt][2] * inv) | ((u32)f2bf(o[vt][3] * inv) << 16);
        *(uint2*)(cp + vt * 16 + quad * 4) = pk;
    }
}

extern "C" void kernel_launch(void* const* d_in, const int* in_sizes, int n_in,
                              void* d_out, int out_size, void* d_ws, size_t ws_size,
                              hipStream_t stream) {
    const float* q    = (const float*)d_in[0];
    const float* k    = (const float*)d_in[1];
    const float* v    = (const float*)d_in[2];
    const float* WQ   = (const float*)d_in[3];
    const float* WK   = (const float*)d_in[4];
    const float* WV   = (const float*)d_in[5];
    const float* Wout = (const float*)d_in[6];
    float* out = (float*)d_out;
    u16*  Xbf = (u16*)d_out;            // d_out doubles as bf16 scratch (33.5 MB)

    // ws: [3][B*H*S*64] bf16 (wq, wk, wvT) 50.3 MB + [4][512*512] bf16 2 MB
    const size_t per = (size_t)BATCH * NHEAD * S_LEN * KHD;
    u16* wsQKV = (u16*)d_ws;
    u16* wsW   = wsQKV + 3 * per;

    // 1. weights -> bf16
    wcvt_kernel<<<dim3(256, 4), 256, 0, stream>>>(WQ, WK, WV, Wout, wsW);

    // 2. q,k -> bf16 into d_out (two halves)
    xcvt_kernel<<<dim3(NROW * DMODEL / 1024, 2), 256, 0, stream>>>(q, k, Xbf);

    // 3. q,k projections + norm -> wq, wk
    gemm_kernel<1><<<dim3(NROW / 128, DMODEL / 128, 2), 256, 0, stream>>>(
        Xbf, wsW, wsQKV, nullptr);

    // 4. v -> bf16 into d_out lo half (q-bf16 now dead)
    xcvt_kernel<<<dim3(NROW * DMODEL / 1024, 1), 256, 0, stream>>>(v, v, Xbf);

    // 5. v projection + norm -> transposed wvT [B][H][64][S]
    gemm_kernel<2><<<dim3(S_LEN / 128, DMODEL / 128, BATCH), 256, 0, stream>>>(
        Xbf, wsW + (size_t)2 * DMODEL * DMODEL, wsQKV + 2 * per, nullptr);

    // 6. attention -> bf16 concat into d_out lo half
    attn_kernel<<<dim3(S_LEN / 64, BATCH * NHEAD), 256, 0, stream>>>(
        wsQKV, wsQKV + per, wsQKV + 2 * per, Xbf);

    // 7. move bf16 concat into ws (wq region is dead) so out-proj can write
    //    d_out without racing its own input
    hipMemcpyAsync(wsQKV, Xbf, (size_t)NROW * DMODEL * sizeof(u16),
                   hipMemcpyDeviceToDevice, stream);

    // 8. output projection -> fp32 d_out
    gemm_kernel<0><<<dim3(NROW / 128, DMODEL / 128, 1), 256, 0, stream>>>(
        wsQKV, wsW + (size_t)3 * DMODEL * DMODEL, nullptr, out);
}